// Round 8
// baseline (345.677 us; speedup 1.0000x reference)
//
#include <hip/hip_runtime.h>
#include <hip/hip_bf16.h>
#include <math.h>

#define NCLS 19
#define MCOMP 5
#define AFEAT 64
#define IGNORE_L 255
#define LOG2PI 1.8378770664093453f

// 20 classes x 8 component-slots = 160 rows (slots 5..7 and class 19 are pads)
#define ROWS 160
// ws byte offsets
#define WAM_B 0                      // bf16 [160][128] : 40960 B  ([nl | iv])
#define WAL_B 40960                  // bf16 [160][64]  : 20480 B  (loc)
#define CST_B 61440                  // f32  [160]      : 640 B    (pads = 1e30)
#define MT_B  62080                  // bf16 [20][64]   : 2560 B   (row 19 = 0)
#define DR_B  64640                  // f32  [20]       : 80 B     (DR[19] = 0)
#define ACC_B 64768                  // f32  [2]        : sum, cnt
#define VAL_B 64832                  // u64  [4096]     : validity bitmask

typedef __attribute__((ext_vector_type(8))) short bf16x8;
typedef __attribute__((ext_vector_type(4))) float f32x4;

__device__ inline float b2f(short s) {
    return __uint_as_float(((unsigned int)(unsigned short)s) << 16);
}
__device__ inline short f2b(float f) {
    __hip_bfloat16 h = __float2bfloat16(f);
    return *reinterpret_cast<short*>(&h);
}

// ---------------- precompute: permuted bf16 weights + constants ----------------
__global__ void precompute_kernel(const float* __restrict__ mean,
                                  const float* __restrict__ cov,
                                  const float* __restrict__ tmem,
                                  const float* __restrict__ ct,
                                  const float* __restrict__ cs,
                                  char* __restrict__ wsb) {
    int blk = blockIdx.x;
    int a = threadIdx.x;  // 64 threads
    short* wam = (short*)(wsb + WAM_B);
    short* wal = (short*)(wsb + WAL_B);
    float* cst = (float*)(wsb + CST_B);
    short* mtb = (short*)(wsb + MT_B);
    float* dr  = (float*)(wsb + DR_B);
    float* acc = (float*)(wsb + ACC_B);

    if (blk < ROWS) {
        int r = blk, c = r >> 3, m = r & 7;
        if (c < NCLS && m < MCOMP) {
            int k = c * MCOMP + m;
            float lo = mean[k * AFEAT + a];
            float cv = cov[k * AFEAT + a];
            float iv = 1.0f / (cv * cv);
            wam[r * 128 + a]      = f2b(-2.0f * lo * iv);  // k-half 0: pairs with f
            wam[r * 128 + 64 + a] = f2b(iv);               // k-half 1: pairs with q=f^2
            wal[r * 64 + a]       = f2b(lo);
            float s1 = lo * lo * iv;
            float s2 = logf(cv);
            for (int off = 32; off > 0; off >>= 1) {
                s1 += __shfl_xor(s1, off, 64);
                s2 += __shfl_xor(s2, off, 64);
            }
            if (a == 0) cst[r] = AFEAT * LOG2PI + 2.0f * s2 + s1;
        } else {
            wam[r * 128 + a] = 0; wam[r * 128 + 64 + a] = 0;
            wal[r * 64 + a] = 0;
            if (a == 0) cst[r] = 1e30f;   // pad: lp -> -inf
        }
    } else if (blk < ROWS + 20) {
        int c = blk - ROWS;
        if (c < NCLS) {
            const float* p = tmem + ((size_t)c * AFEAT + a) * 100;
            float s = 0.f;
            for (int j = 0; j < 100; ++j) s += p[j];
            s *= 0.01f;
            float n2 = s * s;
            for (int off = 32; off > 0; off >>= 1) n2 += __shfl_xor(n2, off, 64);
            float den = fmaxf(sqrtf(n2), 1e-12f);
            mtb[c * AFEAT + a] = f2b(s / den);
        } else {
            mtb[c * AFEAT + a] = 0;
        }
    } else {
        if (a < 20) {
            float r = 0.f;
            if (a < NCLS) {
                r = ct[a] / cs[a];
                if (isnan(r)) r = 0.f;
                else if (isinf(r)) r = (r > 0.f) ? 3.402823466e38f : -3.402823466e38f;
            }
            dr[a] = r;
        }
        if (a == 32) { acc[0] = 0.f; acc[1] = 0.f; }
    }
}

// ---------------- validity bitmask (majority >= 12/16 of a real class) ----------
__global__ void valid_kernel(const int* __restrict__ mask,
                             unsigned long long* __restrict__ vwords) {
    int n = blockIdx.x * 256 + threadIdx.x;
    int b = n >> 16, rem = n & 65535, y = rem >> 8, x = rem & 255;
    const int* mp = mask + (((size_t)b << 10) + ((size_t)y << 2)) * 1024 + ((size_t)x << 2);
    int v[16];
#pragma unroll
    for (int r = 0; r < 4; ++r) {
        int4 q = *reinterpret_cast<const int4*>(mp + (size_t)r * 1024);
        v[r * 4 + 0] = q.x; v[r * 4 + 1] = q.y; v[r * 4 + 2] = q.z; v[r * 4 + 3] = q.w;
    }
    bool valid = false;
#pragma unroll
    for (int i = 0; i < 16; ++i) {
        int cnt = 0;
#pragma unroll
        for (int j = 0; j < 16; ++j) cnt += (v[j] == v[i]) ? 1 : 0;
        if (v[i] != IGNORE_L && cnt >= 12) valid = true;
    }
    unsigned long long bm = __ballot(valid);
    if ((threadIdx.x & 63) == 0) vwords[n >> 6] = bm;
}

// ---------------- main MFMA kernel: independent class-tiles, 32 px/wave-iter ----
// 512 threads = 8 waves; each wave does 2 iterations of 32 pixels.
__global__ __launch_bounds__(512, 4)
void protogmm_kernel(const float* __restrict__ feat,
                     const char* __restrict__ wsb,
                     const unsigned long long* __restrict__ vwords,
                     float* __restrict__ accg) {
    __shared__ short wamL[ROWS * 128];   // 40960 B, slot-swizzled
    __shared__ short walL[ROWS * 64];    // 20480 B, slot-swizzled
    __shared__ float cstL[ROWS];         // 640 B
    __shared__ short mtL[20 * 64];       // 2560 B
    __shared__ float ldrL[20];           // 80 B (log of dist ratio)

    int tid = threadIdx.x;
    // ---- stage weights to LDS (swizzle 16B slots by row&7)
    {
        const uint4* s0 = (const uint4*)(wsb + WAM_B);
        for (int i = tid; i < 2560; i += 512) {
            int row = i >> 4, slot = i & 15;
            *(uint4*)((char*)wamL + row * 256 + ((slot ^ (row & 7)) << 4)) = s0[i];
        }
        const uint4* s1 = (const uint4*)(wsb + WAL_B);
        for (int i = tid; i < 1280; i += 512) {
            int row = i >> 3, slot = i & 7;
            *(uint4*)((char*)walL + row * 128 + ((slot ^ (row & 7)) << 4)) = s1[i];
        }
        const float* s2 = (const float*)(wsb + CST_B);
        for (int i = tid; i < ROWS; i += 512) cstL[i] = s2[i];
        const uint4* s3 = (const uint4*)(wsb + MT_B);
        for (int i = tid; i < 160; i += 512) ((uint4*)mtL)[i] = s3[i];
        const float* s4 = (const float*)(wsb + DR_B);
        if (tid < 20) ldrL[tid] = __logf(s4[tid]);   // log(0) = -inf for pad
    }
    __syncthreads();

    int lane = tid & 63, l15 = lane & 15, g = lane >> 4, rx = l15 & 7;
    int wv = blockIdx.x * 8 + (tid >> 6);
    int p = g >> 1;  // class parity handled by this lane

    float cesum = 0.f, cntsum = 0.f;

#pragma unroll 1
    for (int it = 0; it < 2; ++it) {
        int n0 = (wv * 2 + it) << 5;             // 32 pixels per iteration
        int b = n0 >> 16, y = (n0 >> 8) & 255, x0 = n0 & 255;

        // ---- load feature chunks for both 16-pixel column sets, norm, pack bf16
        bf16x8 FA[4], FB[4];
        {
            const float* fb = feat + (size_t)b * (AFEAT * 65536) + y * 256 + x0 + l15;
            float aa[8], ac[8], ba[8], bc[8];
            float nA = 0.f, nB = 0.f;
#pragma unroll
            for (int j = 0; j < 8; ++j) {
                aa[j] = fb[(size_t)(8 * g + j) * 65536];
                ac[j] = fb[(size_t)(32 + 8 * g + j) * 65536];
                ba[j] = fb[(size_t)(8 * g + j) * 65536 + 16];
                bc[j] = fb[(size_t)(32 + 8 * g + j) * 65536 + 16];
            }
#pragma unroll
            for (int j = 0; j < 8; ++j) {
                nA = fmaf(aa[j], aa[j], nA); nA = fmaf(ac[j], ac[j], nA);
                nB = fmaf(ba[j], ba[j], nB); nB = fmaf(bc[j], bc[j], nB);
            }
            nA += __shfl_xor(nA, 16, 64); nA += __shfl_xor(nA, 32, 64);
            nB += __shfl_xor(nB, 16, 64); nB += __shfl_xor(nB, 32, 64);
            float iA = 1.0f / fmaxf(sqrtf(nA), 1e-12f);
            float iB = 1.0f / fmaxf(sqrtf(nB), 1e-12f);
#pragma unroll
            for (int j = 0; j < 8; ++j) {
                float u, w2;
                u = aa[j] * iA; w2 = ac[j] * iA;
                FA[0][j] = f2b(u); FA[1][j] = f2b(w2);
                FA[2][j] = f2b(u * u); FA[3][j] = f2b(w2 * w2);
                u = ba[j] * iB; w2 = bc[j] * iB;
                FB[0][j] = f2b(u); FB[1][j] = f2b(w2);
                FB[2][j] = f2b(u * u); FB[3][j] = f2b(w2 * w2);
            }
        }

        // per-set online state (independent across t -> pipelinable)
        float bWA = -3.4e38f, bcA = 0.f, blA = 0.f, lsA = 0.f;
        float bWB = -3.4e38f, bcB = 0.f, blB = 0.f, lsB = 0.f;

#pragma unroll 2
        for (int t = 0; t < 10; ++t) {
            // ---- maha GEMM (weights shared between pixel sets)
            f32x4 cini = *(const f32x4*)(cstL + 16 * t + 4 * g);
            f32x4 aA = cini, aB = cini;
#pragma unroll
            for (int kt = 0; kt < 4; ++kt) {
                bf16x8 wa = *(const bf16x8*)((char*)wamL + (16 * t + l15) * 256 +
                                             (((4 * kt + g) ^ rx) << 4));
                aA = __builtin_amdgcn_mfma_f32_16x16x32_bf16(wa, FA[kt], aA, 0, 0, 0);
                aB = __builtin_amdgcn_mfma_f32_16x16x32_bf16(wa, FB[kt], aB, 0, 0, 0);
            }
            // ---- logits GEMM
            f32x4 qA = {0.f, 0.f, 0.f, 0.f}, qB = {0.f, 0.f, 0.f, 0.f};
#pragma unroll
            for (int kt = 0; kt < 2; ++kt) {
                bf16x8 wl = *(const bf16x8*)((char*)walL + (16 * t + l15) * 128 +
                                             (((4 * kt + g) ^ rx) << 4));
                qA = __builtin_amdgcn_mfma_f32_16x16x32_bf16(wl, FA[kt], qA, 0, 0, 0);
                qB = __builtin_amdgcn_mfma_f32_16x16x32_bf16(wl, FB[kt], qB, 0, 0, 0);
            }

            // ---- per-class logits max (mask pad m-slots; class pad at t=9,g>=2)
            bool mpad = (g & 1), cpad = (t == 9) && (g & 2);
            float lmA, lmB;
            {
                float d0 = qA[0] * 0.01f, d1 = qA[1] * 0.01f;
                float d2 = qA[2] * 0.01f, d3 = qA[3] * 0.01f;
                if (mpad) { d1 = -1e30f; d2 = -1e30f; d3 = -1e30f; }
                float lt = fmaxf(fmaxf(d0, d1), fmaxf(d2, d3));
                if (cpad) lt = -1e30f;
                lmA = fmaxf(lt, __shfl_xor(lt, 16, 64));
                d0 = qB[0] * 0.01f; d1 = qB[1] * 0.01f;
                d2 = qB[2] * 0.01f; d3 = qB[3] * 0.01f;
                if (mpad) { d1 = -1e30f; d2 = -1e30f; d3 = -1e30f; }
                lt = fmaxf(fmaxf(d0, d1), fmaxf(d2, d3));
                if (cpad) lt = -1e30f;
                lmB = fmaxf(lt, __shfl_xor(lt, 16, 64));
            }
            lsA += __expf(lmA);
            lsB += __expf(lmB);

            // ---- per-class maha LSE (xor16 only: class spans one g-pair)
            float lseA, lseB;
            {
                float mn = fminf(fminf(aA[0], aA[1]), fminf(aA[2], aA[3]));
                mn = fminf(mn, __shfl_xor(mn, 16, 64));
                float mx = -0.5f * mn;
                float e0 = __expf(fmaf(aA[0], -0.5f, -mx));
                float e1 = __expf(fmaf(aA[1], -0.5f, -mx));
                float e2 = __expf(fmaf(aA[2], -0.5f, -mx));
                float e3 = __expf(fmaf(aA[3], -0.5f, -mx));
                float st = (e0 + e1) + (e2 + e3);
                lseA = mx + __logf(st + __shfl_xor(st, 16, 64));
                mn = fminf(fminf(aB[0], aB[1]), fminf(aB[2], aB[3]));
                mn = fminf(mn, __shfl_xor(mn, 16, 64));
                mx = -0.5f * mn;
                e0 = __expf(fmaf(aB[0], -0.5f, -mx));
                e1 = __expf(fmaf(aB[1], -0.5f, -mx));
                e2 = __expf(fmaf(aB[2], -0.5f, -mx));
                e3 = __expf(fmaf(aB[3], -0.5f, -mx));
                st = (e0 + e1) + (e2 + e3);
                lseB = mx + __logf(st + __shfl_xor(st, 16, 64));
            }

            // ---- sim dots (reads shared across sets)
            float sdA, sdB;
            {
                const short* m0 = mtL + (2 * t) * 64 + 8 * g;
                const short* m1 = mtL + (2 * t + 1) * 64 + 8 * g;
                float p0A = 0.f, p1A = 0.f, p0B = 0.f, p1B = 0.f;
#pragma unroll
                for (int j = 0; j < 8; ++j) {
                    float w0 = b2f(m0[j]), w1 = b2f(m0[32 + j]);
                    float v0 = b2f(m1[j]), v1 = b2f(m1[32 + j]);
                    float uA = b2f(FA[0][j]), cA = b2f(FA[1][j]);
                    float uB = b2f(FB[0][j]), cB = b2f(FB[1][j]);
                    p0A = fmaf(uA, w0, p0A); p0A = fmaf(cA, w1, p0A);
                    p1A = fmaf(uA, v0, p1A); p1A = fmaf(cA, v1, p1A);
                    p0B = fmaf(uB, w0, p0B); p0B = fmaf(cB, w1, p0B);
                    p1B = fmaf(uB, v0, p1B); p1B = fmaf(cB, v1, p1B);
                }
                p0A += __shfl_xor(p0A, 16, 64); p0A += __shfl_xor(p0A, 32, 64);
                p1A += __shfl_xor(p1A, 16, 64); p1A += __shfl_xor(p1A, 32, 64);
                p0B += __shfl_xor(p0B, 16, 64); p0B += __shfl_xor(p0B, 32, 64);
                p1B += __shfl_xor(p1B, 16, 64); p1B += __shfl_xor(p1B, 32, 64);
                sdA = p ? p1A : p0A;
                sdB = p ? p1B : p0B;
            }

            // ---- log-space value compare (denominators are monotone-invariant)
            float ldr = ldrL[2 * t + p];
            float WA = ldr + sdA + lseA;
            float WB = ldr + sdB + lseB;
            float cls = (float)(2 * t + p);
            if (WA > bWA) { bWA = WA; bcA = cls; blA = lmA; }
            if (WB > bWB) { bWB = WB; bcB = cls; blB = lmB; }
        }

        // ---- merge other parity (xor32); xor16 partner identical by construction
        {
            float ov = __shfl_xor(bWA, 32, 64);
            float oc = __shfl_xor(bcA, 32, 64);
            float ol = __shfl_xor(blA, 32, 64);
            bool take = (ov > bWA) || (ov == bWA && oc < bcA);
            bWA = take ? ov : bWA; blA = take ? ol : blA; bcA = take ? oc : bcA;
            lsA += __shfl_xor(lsA, 32, 64);
            ov = __shfl_xor(bWB, 32, 64);
            oc = __shfl_xor(bcB, 32, 64);
            ol = __shfl_xor(blB, 32, 64);
            take = (ov > bWB) || (ov == bWB && oc < bcB);
            bWB = take ? ov : bWB; blB = take ? ol : blB; bcB = take ? oc : bcB;
            lsB += __shfl_xor(lsB, 32, 64);
        }
        float ceA = __logf(lsA) - blA;
        float ceB = __logf(lsB) - blB;

        // ---- validity + accumulate (count each pixel once: g==0 lanes)
        unsigned long long w = vwords[n0 >> 6];
        float vbA = (float)((w >> ((n0 & 63) + l15)) & 1ull);
        float vbB = (float)((w >> ((n0 & 63) + 16 + l15)) & 1ull);
        if (g == 0) {
            cesum = fmaf(vbA, ceA, cesum);
            cesum = fmaf(vbB, ceB, cesum);
            cntsum += vbA + vbB;
        }
    }

    // ---- wave reduce + atomic
#pragma unroll
    for (int off = 32; off > 0; off >>= 1) {
        cesum  += __shfl_xor(cesum, off, 64);
        cntsum += __shfl_xor(cntsum, off, 64);
    }
    if (lane == 0) {
        atomicAdd(&accg[0], cesum);
        atomicAdd(&accg[1], cntsum);
    }
}

__global__ void finalize_kernel(const float* __restrict__ acc, float* __restrict__ out) {
    out[0] = acc[0] / fmaxf(acc[1], 1.0f);
}

extern "C" void kernel_launch(void* const* d_in, const int* in_sizes, int n_in,
                              void* d_out, int out_size, void* d_ws, size_t ws_size,
                              hipStream_t stream) {
    const float* feat = (const float*)d_in[0];
    const int*   mask = (const int*)d_in[1];
    const float* mean = (const float*)d_in[2];
    const float* cov  = (const float*)d_in[3];
    const float* tmem = (const float*)d_in[4];
    const float* ct   = (const float*)d_in[5];
    const float* cs   = (const float*)d_in[6];
    float* out = (float*)d_out;
    char*  wsb = (char*)d_ws;

    precompute_kernel<<<ROWS + 20 + 1, 64, 0, stream>>>(mean, cov, tmem, ct, cs, wsb);
    valid_kernel<<<1024, 256, 0, stream>>>(mask, (unsigned long long*)(wsb + VAL_B));
    protogmm_kernel<<<512, 512, 0, stream>>>(feat, wsb,
                                             (const unsigned long long*)(wsb + VAL_B),
                                             (float*)(wsb + ACC_B));
    finalize_kernel<<<1, 1, 0, stream>>>((const float*)(wsb + ACC_B), out);
}